// Round 16
// baseline (102.991 us; speedup 1.0000x reference)
//
#include <hip/hip_runtime.h>
#include <hip/hip_bf16.h>

typedef unsigned short u16;
typedef float f32x4 __attribute__((ext_vector_type(4)));
typedef __bf16 bf16x8 __attribute__((ext_vector_type(8)));
typedef _Float16 f16x8 __attribute__((ext_vector_type(8)));
typedef _Float16 f16x2 __attribute__((ext_vector_type(2)));

union Frag { int4 i; bf16x8 b; f16x8 h; };

__device__ inline u16 f2bf(float f) {
  union { float f; unsigned u; } v; v.f = f;
  unsigned r = v.u + 0x7FFFu + ((v.u >> 16) & 1u);
  return (u16)(r >> 16);
}
__device__ inline unsigned pk_f16(float a, float b) {  // packed f16 {lo=a, hi=b}, RTZ
  return __builtin_bit_cast(unsigned, __builtin_amdgcn_cvt_pkrtz(a, b));
}

// LDS-only barrier (no vmcnt drain; global loads/stores stay in flight).
__device__ __forceinline__ void lds_barrier() {
  asm volatile("s_waitcnt lgkmcnt(0)" ::: "memory");
  __builtin_amdgcn_s_barrier();
}

// ---------------------------------------------------------------------------
// Projection GEMM body: Y = X @ W.T + bias (X: rows x 128 fp32, W: 128x128)
// mode 0: out f16  head-major  [b][h][row][16]   (q, k)
// mode 1: out f16  transposed  [b][h][16][1024]  (V)
// ---------------------------------------------------------------------------
__device__ __forceinline__
void proj_body(u16* __restrict__ smem,
               const float* __restrict__ X, const float* __restrict__ W,
               const float* __restrict__ bias, void* __restrict__ out,
               int mode, int innerShift, int rows0)
{
  u16* XL = smem;              // [64][136]
  u16* WL = smem + 64 * 136;   // [128][136]

  const int tid = threadIdx.x;
  const int w = tid >> 6, l = tid & 63, lg = l >> 4, lr = l & 15;

  #pragma unroll
  for (int i = 0; i < 8; ++i) {
    int u = tid + i * 256;
    int rr = u >> 5, c4 = (u & 31) * 4;
    const float4 xv = *(const float4*)(X + (rows0 + rr) * 128 + c4);
    uint2 p;
    p.x = (unsigned)f2bf(xv.x) | ((unsigned)f2bf(xv.y) << 16);
    p.y = (unsigned)f2bf(xv.z) | ((unsigned)f2bf(xv.w) << 16);
    *(uint2*)(XL + rr * 136 + c4) = p;
  }
  #pragma unroll
  for (int i = 0; i < 16; ++i) {
    int u = tid + i * 256;
    int rr = u >> 5, c4 = (u & 31) * 4;
    const float4 xv = *(const float4*)(W + rr * 128 + c4);
    uint2 p;
    p.x = (unsigned)f2bf(xv.x) | ((unsigned)f2bf(xv.y) << 16);
    p.y = (unsigned)f2bf(xv.z) | ((unsigned)f2bf(xv.w) << 16);
    *(uint2*)(WL + rr * 136 + c4) = p;
  }
  __syncthreads();

  Frag a[4];
  #pragma unroll
  for (int kc = 0; kc < 4; ++kc)
    a[kc].i = *(const int4*)(XL + (16 * w + lr) * 136 + kc * 32 + 8 * lg);

  f32x4 acc[8];
  #pragma unroll
  for (int ct = 0; ct < 8; ++ct) {
    f32x4 c = {0.f, 0.f, 0.f, 0.f};
    #pragma unroll
    for (int kc = 0; kc < 4; ++kc) {
      Frag bw;
      bw.i = *(const int4*)(WL + (ct * 16 + lr) * 136 + kc * 32 + 8 * lg);
      c = __builtin_amdgcn_mfma_f32_16x16x32_bf16(a[kc].b, bw.b, c, 0, 0, 0);
    }
    acc[ct] = c;
  }

  if (mode == 0) {  // f16 head-major (q, k)
    u16* o = (u16*)out;
    const int innerMask = (1 << innerShift) - 1;
    #pragma unroll
    for (int ct = 0; ct < 8; ++ct) {
      float bn = bias[ct * 16 + lr];
      #pragma unroll
      for (int j = 0; j < 4; ++j) {
        int row = rows0 + 16 * w + 4 * lg + j;
        int bI = row >> innerShift, r = row & innerMask;
        o[(((bI * 8 + ct) << innerShift) + r) * 16 + lr] =
            __builtin_bit_cast(u16, (_Float16)(acc[ct][j] + bn));
      }
    }
  } else { // mode 1: f16 transposed via LDS
    __syncthreads();
    u16* YT = smem; // [128][72]
    #pragma unroll
    for (int ct = 0; ct < 8; ++ct) {
      float bn = bias[ct * 16 + lr];
      #pragma unroll
      for (int j = 0; j < 4; ++j)
        YT[(ct * 16 + lr) * 72 + 16 * w + 4 * lg + j] =
            __builtin_bit_cast(u16, (_Float16)(acc[ct][j] + bn));
    }
    __syncthreads();
    u16* o = (u16*)out;
    const int bI = rows0 >> 10, s0 = rows0 & 1023;
    #pragma unroll
    for (int i = 0; i < 4; ++i) {
      int u = tid + i * 256;
      int n = u >> 3, ch = (u & 7) * 8;
      int4 v = *(const int4*)(YT + n * 72 + ch);
      *(int4*)(o + ((bI * 8 + (n >> 4)) * 16 + (n & 15)) * 1024 + s0 + ch) = v;
    }
  }
}

__global__ __launch_bounds__(256, 2)
void proj_qkv(const float* __restrict__ Q, const float* __restrict__ K,
              const float* __restrict__ V,
              const float* __restrict__ Wq, const float* __restrict__ bq,
              const float* __restrict__ Wk, const float* __restrict__ bk,
              const float* __restrict__ Wv, const float* __restrict__ bv,
              u16* __restrict__ qb, u16* __restrict__ kb, u16* __restrict__ vtb)
{
  __shared__ __attribute__((aligned(16))) u16 smem[26112];
  const int bid = blockIdx.x;
  if (bid < 64)       proj_body(smem, Q, Wq, bq, qb,  0,  9, bid * 64);
  else if (bid < 192) proj_body(smem, K, Wk, bk, kb,  0, 10, (bid - 64) * 64);
  else                proj_body(smem, V, Wv, bv, vtb, 1, 10, (bid - 192) * 64);
}

// ---------------------------------------------------------------------------
// Out-projection, col-quarter split for full CU fill: 256 blocks.
// Block = 64 rows (rt = bid>>2) x 32 output cols (cq = bid&3).
// ---------------------------------------------------------------------------
__global__ __launch_bounds__(256, 2)
void proj_out_kernel(const float* __restrict__ X, const float* __restrict__ W,
                     const float* __restrict__ bias, float* __restrict__ out)
{
  __shared__ __attribute__((aligned(16))) u16 smem[13056]; // XL[64][136]+WL[32][136]
  u16* XL = smem;              // [64][136]
  u16* WL = smem + 64 * 136;   // [32][136]

  const int tid = threadIdx.x;
  const int w = tid >> 6, l = tid & 63, lg = l >> 4, lr = l & 15;
  const int rows0 = (blockIdx.x >> 2) * 64;
  const int c0 = (blockIdx.x & 3) * 32;

  #pragma unroll
  for (int i = 0; i < 8; ++i) {
    int u = tid + i * 256;
    int rr = u >> 5, c4 = (u & 31) * 4;
    const float4 xv = *(const float4*)(X + (rows0 + rr) * 128 + c4);
    uint2 p;
    p.x = (unsigned)f2bf(xv.x) | ((unsigned)f2bf(xv.y) << 16);
    p.y = (unsigned)f2bf(xv.z) | ((unsigned)f2bf(xv.w) << 16);
    *(uint2*)(XL + rr * 136 + c4) = p;
  }
  #pragma unroll
  for (int i = 0; i < 4; ++i) {
    int u = tid + i * 256;
    int rr = u >> 5, c4 = (u & 31) * 4;
    const float4 xv = *(const float4*)(W + (c0 + rr) * 128 + c4);
    uint2 p;
    p.x = (unsigned)f2bf(xv.x) | ((unsigned)f2bf(xv.y) << 16);
    p.y = (unsigned)f2bf(xv.z) | ((unsigned)f2bf(xv.w) << 16);
    *(uint2*)(WL + rr * 136 + c4) = p;
  }
  __syncthreads();

  Frag a[4];
  #pragma unroll
  for (int kc = 0; kc < 4; ++kc)
    a[kc].i = *(const int4*)(XL + (16 * w + lr) * 136 + kc * 32 + 8 * lg);

  #pragma unroll
  for (int ct = 0; ct < 2; ++ct) {
    f32x4 c = {0.f, 0.f, 0.f, 0.f};
    #pragma unroll
    for (int kc = 0; kc < 4; ++kc) {
      Frag bw;
      bw.i = *(const int4*)(WL + (ct * 16 + lr) * 136 + kc * 32 + 8 * lg);
      c = __builtin_amdgcn_mfma_f32_16x16x32_bf16(a[kc].b, bw.b, c, 0, 0, 0);
    }
    float bn = bias[c0 + ct * 16 + lr];
    #pragma unroll
    for (int j = 0; j < 4; ++j) {
      int row = rows0 + 16 * w + 4 * lg + j;
      out[row * 128 + c0 + ct * 16 + lr] = c[j] + bn;
    }
  }
}

// ---------------------------------------------------------------------------
// Fused attention (R16 = R15 + prev loads now CACHED too; single change).
// R15 proved NT stores cost ~10 us (4.0 -> ~5 TB/s effective). Symmetric
// test: prev's 134 MB NT read stream -> plain loads. prev is read once;
// transient L2 occupancy should not evict kb/vtb (512 KB/XCD) materially.
// Pre-A: gated-off rs zeros + e slots + masked-attn zeros (overlap QK^T).
// Phase A: swapped QK^T mfma(k,q) -> scores f16 in SRS (gated-on only).
// Phase B: gated-on chunks only. PV before attn stores. lds_barrier.
// LDS 32768 B exactly -> 5 blocks/CU; __launch_bounds__(256,5).
// ---------------------------------------------------------------------------
__device__ __forceinline__ int swz(int row, int elem) {
  return row * 1024 + (elem ^ ((row & 7) << 3));
}

__global__ __launch_bounds__(256, 5)
void attn_kernel(const u16* __restrict__ qb, const u16* __restrict__ kb,
                 const u16* __restrict__ vtb, const float* __restrict__ prev,
                 const float* __restrict__ ch_gate,
                 float* __restrict__ rs_out, float* __restrict__ attn_out,
                 float* __restrict__ preout)
{
  __shared__ __attribute__((aligned(16))) u16 SRS[16384];  // 32768 B exactly

  const int bid = blockIdx.x;
  const int vb = (bid & 7) * 256 + (bid >> 3);  // XCD swizzle: one batch per XCD
  const int pt = vb & 31, h = (vb >> 5) & 7, b = vb >> 8;
  const int p0 = pt * 16, ptch = pt >> 2;       // predictor channel
  const int tid = threadIdx.x, w = tid >> 6, l = tid & 63;
  const int lg = l >> 4, lr = l & 15;

  unsigned gbits = 0u;
  #pragma unroll
  for (int j = 0; j < 8; ++j)
    if (ch_gate[ptch * 8 + j] >= 0.f) gbits |= (1u << j);
  gbits = __builtin_amdgcn_readfirstlane(gbits);

  const int r = 4 * w + lg;                      // row this thread streams
  const int base = ((b * 512 + p0) * 8 + h) * 1024;
  const float* prow = prev + base + r * 8192;
  float* rsrow = rs_out + base + r * 8192;
  float* arow  = attn_out + base + r * 8192;

  const f32x4 zf = {0.f, 0.f, 0.f, 0.f};
  f32x4 pf0 = (gbits & 1u) ? *(const f32x4*)(prow +   0 + lr * 4) : zf;
  f32x4 pf1 = (gbits & 1u) ? *(const f32x4*)(prow +  64 + lr * 4) : zf;
  f32x4 pf2 = (gbits & 2u) ? *(const f32x4*)(prow + 128 + lr * 4) : zf;
  f32x4 pf3 = (gbits & 2u) ? *(const f32x4*)(prow + 192 + lr * 4) : zf;
  f32x4 pf4 = (gbits & 4u) ? *(const f32x4*)(prow + 256 + lr * 4) : zf;
  f32x4 pf5 = (gbits & 4u) ? *(const f32x4*)(prow + 320 + lr * 4) : zf;

  // ---- Pre-A: all data-independent stores (HBM streams under phase A) ----
  float den = 0.f;
  uint2 eh[16];
  #pragma unroll
  for (int it = 0; it < 16; ++it) {
    const int ch = it >> 1;
    const int s = it * 64 + lr * 4;
    if (!((gbits >> ch) & 1u)) {
      *(f32x4*)(rsrow + s) = zf;
      if (ch == ptch) eh[it] = make_uint2(0u, 0u);
      else          { eh[it] = make_uint2(0x3C003C00u, 0x3C003C00u); den += 4.f; }
      *(uint2*)&SRS[swz(r, s)] = eh[it];
    }
    if (ch == ptch)   // attn == 0 for masked channel regardless of gate/den
      *(f32x4*)(arow + s) = zf;
  }

  // ---- Phase A: swapped QK^T -> scores f16 in LDS (gated-on only) ----
  Frag aq;
  if (lg < 2) aq.i = *(const int4*)(qb + (((b * 8 + h) * 512 + p0 + lr) * 16 + 8 * lg));
  else        aq.i = make_int4(0, 0, 0, 0);

  const u16* kbase = kb + (b * 8 + h) * 1024 * 16;
  const int sbase = w * 256;

  #pragma unroll 2
  for (int st = 0; st < 16; ++st) {
    const int s0 = sbase + st * 16;
    if (!((gbits >> (s0 >> 7)) & 1u)) continue;
    Frag bk;
    if (lg < 2) bk.i = *(const int4*)(kbase + (s0 + lr) * 16 + 8 * lg);
    else        bk.i = make_int4(0, 0, 0, 0);
    f32x4 zero = {0.f, 0.f, 0.f, 0.f};
    f32x4 d = __builtin_amdgcn_mfma_f32_16x16x32_f16(bk.h, aq.h, zero, 0, 0, 0);
    uint2 pk2;
    pk2.x = pk_f16(d[0] * 0.25f, d[1] * 0.25f);
    pk2.y = pk_f16(d[2] * 0.25f, d[3] * 0.25f);
    *(uint2*)&SRS[swz(lr, s0 + 4 * lg)] = pk2;
  }
  lds_barrier();                                 // scores visible; stores/loads in flight

  // ---- Phase B: gated-on chunks only ----
  #pragma unroll
  for (int it = 0; it < 16; ++it) {
    const int ch = it >> 1;
    if (!((gbits >> ch) & 1u)) continue;
    const int s = it * 64 + lr * 4;
    const bool msk = (ch == ptch);
    f32x4 pv;
    if      (it == 0) pv = pf0;
    else if (it == 1) pv = pf1;
    else if (it == 2) pv = pf2;
    else if (it == 3) pv = pf3;
    else if (it == 4) pv = pf4;
    else if (it == 5) pv = pf5;
    else pv = *(const f32x4*)(prow + s);
    union { uint2 u; f16x2 hh[2]; } sc;
    sc.u = *(const uint2*)&SRS[swz(r, s)];
    f32x4 rs;
    rs[0] = (float)sc.hh[0][0] + pv[0];
    rs[1] = (float)sc.hh[0][1] + pv[1];
    rs[2] = (float)sc.hh[1][0] + pv[2];
    rs[3] = (float)sc.hh[1][1] + pv[3];
    *(f32x4*)(rsrow + s) = rs;
    if (msk) {
      eh[it] = make_uint2(0u, 0u);
    } else {
      float e0 = __expf(rs[0]);
      float e1 = __expf(rs[1]);
      float e2 = __expf(rs[2]);
      float e3 = __expf(rs[3]);
      den += (e0 + e1) + (e2 + e3);
      eh[it].x = pk_f16(e0, e1);
      eh[it].y = pk_f16(e2, e3);
    }
    *(uint2*)&SRS[swz(r, s)] = eh[it];
  }

  #pragma unroll
  for (int off = 1; off < 16; off <<= 1)
    den += __shfl_xor(den, off);
  const float invd = 1.f / den;                  // den >= 1 always
  lds_barrier();                                 // e visible; stores NOT drained

  // ---- PV: V loads issued here (not queued behind attn stores) ----
  f32x4 acc = {0.f, 0.f, 0.f, 0.f};
  const u16* vbase = vtb + ((b * 8 + h) * 16 + lr) * 1024;
  #pragma unroll
  for (int kc = 0; kc < 8; ++kc) {
    Frag pa, bv;
    pa.i = *(const int4*)(&SRS[swz(lr, sbase + kc * 32 + 8 * lg)]);
    bv.i = *(const int4*)(vbase + sbase + kc * 32 + 8 * lg);
    acc = __builtin_amdgcn_mfma_f32_16x16x32_f16(pa.h, bv.h, acc, 0, 0, 0);
  }

  // ---- epilogue: cross-wave partial sum + DenInv via SRS-as-f32 scratch ----
  lds_barrier();                                 // all waves done reading e
  {
    float* OutBuf = (float*)SRS;                 // [64][20] f32 + DenInv[16]
    #pragma unroll
    for (int j = 0; j < 4; ++j)
      OutBuf[(w * 16 + 4 * lg + j) * 20 + lr] = acc[j];
    if (lr == 0) OutBuf[1280 + r] = invd;
  }
  lds_barrier();
  {
    float* OutBuf = (float*)SRS;
    const int pr = tid >> 4, dd = tid & 15;
    float o = (OutBuf[pr * 20 + dd] + OutBuf[(16 + pr) * 20 + dd] +
               OutBuf[(32 + pr) * 20 + dd] + OutBuf[(48 + pr) * 20 + dd]) *
              OutBuf[1280 + pr];
    preout[((b * 512 + p0 + pr) * 8 + h) * 16 + dd] = o;
  }

  // ---- attn stores LAST (masked channel already written pre-A) ----
  {
    #pragma unroll
    for (int it = 0; it < 16; ++it) {
      const int ch = it >> 1;
      if (ch == ptch) continue;                  // written pre-A
      const int s = it * 64 + lr * 4;
      union { uint2 u; f16x2 hh[2]; } e;
      e.u = eh[it];
      f32x4 o;
      o[0] = (float)e.hh[0][0] * invd;
      o[1] = (float)e.hh[0][1] * invd;
      o[2] = (float)e.hh[1][0] * invd;
      o[3] = (float)e.hh[1][1] * invd;
      *(f32x4*)(arow + s) = o;
    }
  }
}

// ---------------------------------------------------------------------------
extern "C" void kernel_launch(void* const* d_in, const int* in_sizes, int n_in,
                              void* d_out, int out_size, void* d_ws, size_t ws_size,
                              hipStream_t stream)
{
  (void)in_sizes; (void)n_in; (void)out_size; (void)ws_size;
  const float* Q       = (const float*)d_in[0];
  const float* K       = (const float*)d_in[1];
  const float* V       = (const float*)d_in[2];
  const float* prev    = (const float*)d_in[3];
  const float* Wq      = (const float*)d_in[5];
  const float* bq      = (const float*)d_in[6];
  const float* Wk      = (const float*)d_in[7];
  const float* bk      = (const float*)d_in[8];
  const float* Wv      = (const float*)d_in[9];
  const float* bv      = (const float*)d_in[10];
  const float* Wo      = (const float*)d_in[11];
  const float* bo      = (const float*)d_in[12];
  const float* ch_gate = (const float*)d_in[13];

  u16*   qb     = (u16*)d_ws;                        // 1 MB f16
  u16*   kb     = qb + 524288;                       // 2 MB f16
  u16*   vtb    = kb + 1048576;                      // 2 MB f16
  float* preout = (float*)((char*)d_ws + 5242880);   // 2 MB fp32

  float* outp     = (float*)d_out;          // (B,P,128)
  float* attn_out = outp + 524288;          // (B,P,H,S)
  float* rs_out   = outp + 34078720;        // (B,P,H,S)

  proj_qkv<<<320, 256, 0, stream>>>(Q, K, V, Wq, bq, Wk, bk, Wv, bv,
                                    qb, kb, vtb);
  attn_kernel<<<2048, 256, 0, stream>>>(qb, kb, vtb, prev, ch_gate,
                                        rs_out, attn_out, preout);
  proj_out_kernel<<<256, 256, 0, stream>>>(preout, Wo, bo, outp);
}

// Round 17
// 86.416 us; speedup vs baseline: 1.1918x; 1.1918x over previous
//
#include <hip/hip_runtime.h>
#include <hip/hip_bf16.h>

typedef unsigned short u16;
typedef float f32x4 __attribute__((ext_vector_type(4)));
typedef __bf16 bf16x8 __attribute__((ext_vector_type(8)));
typedef _Float16 f16x8 __attribute__((ext_vector_type(8)));
typedef _Float16 f16x2 __attribute__((ext_vector_type(2)));

union Frag { int4 i; bf16x8 b; f16x8 h; };

__device__ inline u16 f2bf(float f) {
  union { float f; unsigned u; } v; v.f = f;
  unsigned r = v.u + 0x7FFFu + ((v.u >> 16) & 1u);
  return (u16)(r >> 16);
}
__device__ inline unsigned pk_f16(float a, float b) {  // packed f16 {lo=a, hi=b}, RTZ
  return __builtin_bit_cast(unsigned, __builtin_amdgcn_cvt_pkrtz(a, b));
}

// LDS-only barrier (no vmcnt drain; global loads/stores stay in flight).
__device__ __forceinline__ void lds_barrier() {
  asm volatile("s_waitcnt lgkmcnt(0)" ::: "memory");
  __builtin_amdgcn_s_barrier();
}

// ---------------------------------------------------------------------------
// Projection GEMM body: Y = X @ W.T + bias (X: rows x 128 fp32, W: 128x128)
// mode 0: out f16  head-major  [b][h][row][16]   (q, k)
// mode 1: out f16  transposed  [b][h][16][1024]  (V)
// ---------------------------------------------------------------------------
__device__ __forceinline__
void proj_body(u16* __restrict__ smem,
               const float* __restrict__ X, const float* __restrict__ W,
               const float* __restrict__ bias, void* __restrict__ out,
               int mode, int innerShift, int rows0)
{
  u16* XL = smem;              // [64][136]
  u16* WL = smem + 64 * 136;   // [128][136]

  const int tid = threadIdx.x;
  const int w = tid >> 6, l = tid & 63, lg = l >> 4, lr = l & 15;

  #pragma unroll
  for (int i = 0; i < 8; ++i) {
    int u = tid + i * 256;
    int rr = u >> 5, c4 = (u & 31) * 4;
    const float4 xv = *(const float4*)(X + (rows0 + rr) * 128 + c4);
    uint2 p;
    p.x = (unsigned)f2bf(xv.x) | ((unsigned)f2bf(xv.y) << 16);
    p.y = (unsigned)f2bf(xv.z) | ((unsigned)f2bf(xv.w) << 16);
    *(uint2*)(XL + rr * 136 + c4) = p;
  }
  #pragma unroll
  for (int i = 0; i < 16; ++i) {
    int u = tid + i * 256;
    int rr = u >> 5, c4 = (u & 31) * 4;
    const float4 xv = *(const float4*)(W + rr * 128 + c4);
    uint2 p;
    p.x = (unsigned)f2bf(xv.x) | ((unsigned)f2bf(xv.y) << 16);
    p.y = (unsigned)f2bf(xv.z) | ((unsigned)f2bf(xv.w) << 16);
    *(uint2*)(WL + rr * 136 + c4) = p;
  }
  __syncthreads();

  Frag a[4];
  #pragma unroll
  for (int kc = 0; kc < 4; ++kc)
    a[kc].i = *(const int4*)(XL + (16 * w + lr) * 136 + kc * 32 + 8 * lg);

  f32x4 acc[8];
  #pragma unroll
  for (int ct = 0; ct < 8; ++ct) {
    f32x4 c = {0.f, 0.f, 0.f, 0.f};
    #pragma unroll
    for (int kc = 0; kc < 4; ++kc) {
      Frag bw;
      bw.i = *(const int4*)(WL + (ct * 16 + lr) * 136 + kc * 32 + 8 * lg);
      c = __builtin_amdgcn_mfma_f32_16x16x32_bf16(a[kc].b, bw.b, c, 0, 0, 0);
    }
    acc[ct] = c;
  }

  if (mode == 0) {  // f16 head-major (q, k)
    u16* o = (u16*)out;
    const int innerMask = (1 << innerShift) - 1;
    #pragma unroll
    for (int ct = 0; ct < 8; ++ct) {
      float bn = bias[ct * 16 + lr];
      #pragma unroll
      for (int j = 0; j < 4; ++j) {
        int row = rows0 + 16 * w + 4 * lg + j;
        int bI = row >> innerShift, r = row & innerMask;
        o[(((bI * 8 + ct) << innerShift) + r) * 16 + lr] =
            __builtin_bit_cast(u16, (_Float16)(acc[ct][j] + bn));
      }
    }
  } else { // mode 1: f16 transposed via LDS
    __syncthreads();
    u16* YT = smem; // [128][72]
    #pragma unroll
    for (int ct = 0; ct < 8; ++ct) {
      float bn = bias[ct * 16 + lr];
      #pragma unroll
      for (int j = 0; j < 4; ++j)
        YT[(ct * 16 + lr) * 72 + 16 * w + 4 * lg + j] =
            __builtin_bit_cast(u16, (_Float16)(acc[ct][j] + bn));
    }
    __syncthreads();
    u16* o = (u16*)out;
    const int bI = rows0 >> 10, s0 = rows0 & 1023;
    #pragma unroll
    for (int i = 0; i < 4; ++i) {
      int u = tid + i * 256;
      int n = u >> 3, ch = (u & 7) * 8;
      int4 v = *(const int4*)(YT + n * 72 + ch);
      *(int4*)(o + ((bI * 8 + (n >> 4)) * 16 + (n & 15)) * 1024 + s0 + ch) = v;
    }
  }
}

__global__ __launch_bounds__(256, 2)
void proj_qkv(const float* __restrict__ Q, const float* __restrict__ K,
              const float* __restrict__ V,
              const float* __restrict__ Wq, const float* __restrict__ bq,
              const float* __restrict__ Wk, const float* __restrict__ bk,
              const float* __restrict__ Wv, const float* __restrict__ bv,
              u16* __restrict__ qb, u16* __restrict__ kb, u16* __restrict__ vtb)
{
  __shared__ __attribute__((aligned(16))) u16 smem[26112];
  const int bid = blockIdx.x;
  if (bid < 64)       proj_body(smem, Q, Wq, bq, qb,  0,  9, bid * 64);
  else if (bid < 192) proj_body(smem, K, Wk, bk, kb,  0, 10, (bid - 64) * 64);
  else                proj_body(smem, V, Wv, bv, vtb, 1, 10, (bid - 192) * 64);
}

// ---------------------------------------------------------------------------
// Out-projection, col-quarter split for full CU fill: 256 blocks.
// Block = 64 rows (rt = bid>>2) x 32 output cols (cq = bid&3).
// ---------------------------------------------------------------------------
__global__ __launch_bounds__(256, 2)
void proj_out_kernel(const float* __restrict__ X, const float* __restrict__ W,
                     const float* __restrict__ bias, float* __restrict__ out)
{
  __shared__ __attribute__((aligned(16))) u16 smem[13056]; // XL[64][136]+WL[32][136]
  u16* XL = smem;              // [64][136]
  u16* WL = smem + 64 * 136;   // [32][136]

  const int tid = threadIdx.x;
  const int w = tid >> 6, l = tid & 63, lg = l >> 4, lr = l & 15;
  const int rows0 = (blockIdx.x >> 2) * 64;
  const int c0 = (blockIdx.x & 3) * 32;

  #pragma unroll
  for (int i = 0; i < 8; ++i) {
    int u = tid + i * 256;
    int rr = u >> 5, c4 = (u & 31) * 4;
    const float4 xv = *(const float4*)(X + (rows0 + rr) * 128 + c4);
    uint2 p;
    p.x = (unsigned)f2bf(xv.x) | ((unsigned)f2bf(xv.y) << 16);
    p.y = (unsigned)f2bf(xv.z) | ((unsigned)f2bf(xv.w) << 16);
    *(uint2*)(XL + rr * 136 + c4) = p;
  }
  #pragma unroll
  for (int i = 0; i < 4; ++i) {
    int u = tid + i * 256;
    int rr = u >> 5, c4 = (u & 31) * 4;
    const float4 xv = *(const float4*)(W + (c0 + rr) * 128 + c4);
    uint2 p;
    p.x = (unsigned)f2bf(xv.x) | ((unsigned)f2bf(xv.y) << 16);
    p.y = (unsigned)f2bf(xv.z) | ((unsigned)f2bf(xv.w) << 16);
    *(uint2*)(WL + rr * 136 + c4) = p;
  }
  __syncthreads();

  Frag a[4];
  #pragma unroll
  for (int kc = 0; kc < 4; ++kc)
    a[kc].i = *(const int4*)(XL + (16 * w + lr) * 136 + kc * 32 + 8 * lg);

  #pragma unroll
  for (int ct = 0; ct < 2; ++ct) {
    f32x4 c = {0.f, 0.f, 0.f, 0.f};
    #pragma unroll
    for (int kc = 0; kc < 4; ++kc) {
      Frag bw;
      bw.i = *(const int4*)(WL + (ct * 16 + lr) * 136 + kc * 32 + 8 * lg);
      c = __builtin_amdgcn_mfma_f32_16x16x32_bf16(a[kc].b, bw.b, c, 0, 0, 0);
    }
    float bn = bias[c0 + ct * 16 + lr];
    #pragma unroll
    for (int j = 0; j < 4; ++j) {
      int row = rows0 + 16 * w + 4 * lg + j;
      out[row * 128 + c0 + ct * 16 + lr] = c[j] + bn;
    }
  }
}

// ---------------------------------------------------------------------------
// Fused attention (R17 = exact R15 revert; best known = 88.3 us).
// Memory-path policy (both directions HW-confirmed):
//   - prev: NT loads   (single-use 134 MB stream; caching it thrashes L2,
//     evicts kb/vtb, fights write-combining — R16: +14.7 us)
//   - rs/attn: CACHED stores (NT stores bypass L2 write-combining —
//     R15: -10.2 us vs NT)
// Pre-A: gated-off rs zeros + e slots + masked-attn zeros (overlap QK^T).
// Phase A: swapped QK^T mfma(k,q) -> scores f16 in SRS (gated-on only).
// Phase B: gated-on chunks only. PV before attn stores. lds_barrier.
// LDS 32768 B exactly -> 5 blocks/CU; __launch_bounds__(256,5).
// ---------------------------------------------------------------------------
__device__ __forceinline__ int swz(int row, int elem) {
  return row * 1024 + (elem ^ ((row & 7) << 3));
}

__global__ __launch_bounds__(256, 5)
void attn_kernel(const u16* __restrict__ qb, const u16* __restrict__ kb,
                 const u16* __restrict__ vtb, const float* __restrict__ prev,
                 const float* __restrict__ ch_gate,
                 float* __restrict__ rs_out, float* __restrict__ attn_out,
                 float* __restrict__ preout)
{
  __shared__ __attribute__((aligned(16))) u16 SRS[16384];  // 32768 B exactly

  const int bid = blockIdx.x;
  const int vb = (bid & 7) * 256 + (bid >> 3);  // XCD swizzle: one batch per XCD
  const int pt = vb & 31, h = (vb >> 5) & 7, b = vb >> 8;
  const int p0 = pt * 16, ptch = pt >> 2;       // predictor channel
  const int tid = threadIdx.x, w = tid >> 6, l = tid & 63;
  const int lg = l >> 4, lr = l & 15;

  unsigned gbits = 0u;
  #pragma unroll
  for (int j = 0; j < 8; ++j)
    if (ch_gate[ptch * 8 + j] >= 0.f) gbits |= (1u << j);
  gbits = __builtin_amdgcn_readfirstlane(gbits);

  const int r = 4 * w + lg;                      // row this thread streams
  const int base = ((b * 512 + p0) * 8 + h) * 1024;
  const float* prow = prev + base + r * 8192;
  float* rsrow = rs_out + base + r * 8192;
  float* arow  = attn_out + base + r * 8192;

  const f32x4 zf = {0.f, 0.f, 0.f, 0.f};
  f32x4 pf0 = (gbits & 1u) ? __builtin_nontemporal_load((const f32x4*)(prow +   0 + lr * 4)) : zf;
  f32x4 pf1 = (gbits & 1u) ? __builtin_nontemporal_load((const f32x4*)(prow +  64 + lr * 4)) : zf;
  f32x4 pf2 = (gbits & 2u) ? __builtin_nontemporal_load((const f32x4*)(prow + 128 + lr * 4)) : zf;
  f32x4 pf3 = (gbits & 2u) ? __builtin_nontemporal_load((const f32x4*)(prow + 192 + lr * 4)) : zf;
  f32x4 pf4 = (gbits & 4u) ? __builtin_nontemporal_load((const f32x4*)(prow + 256 + lr * 4)) : zf;
  f32x4 pf5 = (gbits & 4u) ? __builtin_nontemporal_load((const f32x4*)(prow + 320 + lr * 4)) : zf;

  // ---- Pre-A: all data-independent stores (HBM streams under phase A) ----
  float den = 0.f;
  uint2 eh[16];
  #pragma unroll
  for (int it = 0; it < 16; ++it) {
    const int ch = it >> 1;
    const int s = it * 64 + lr * 4;
    if (!((gbits >> ch) & 1u)) {
      *(f32x4*)(rsrow + s) = zf;
      if (ch == ptch) eh[it] = make_uint2(0u, 0u);
      else          { eh[it] = make_uint2(0x3C003C00u, 0x3C003C00u); den += 4.f; }
      *(uint2*)&SRS[swz(r, s)] = eh[it];
    }
    if (ch == ptch)   // attn == 0 for masked channel regardless of gate/den
      *(f32x4*)(arow + s) = zf;
  }

  // ---- Phase A: swapped QK^T -> scores f16 in LDS (gated-on only) ----
  Frag aq;
  if (lg < 2) aq.i = *(const int4*)(qb + (((b * 8 + h) * 512 + p0 + lr) * 16 + 8 * lg));
  else        aq.i = make_int4(0, 0, 0, 0);

  const u16* kbase = kb + (b * 8 + h) * 1024 * 16;
  const int sbase = w * 256;

  #pragma unroll 2
  for (int st = 0; st < 16; ++st) {
    const int s0 = sbase + st * 16;
    if (!((gbits >> (s0 >> 7)) & 1u)) continue;
    Frag bk;
    if (lg < 2) bk.i = *(const int4*)(kbase + (s0 + lr) * 16 + 8 * lg);
    else        bk.i = make_int4(0, 0, 0, 0);
    f32x4 zero = {0.f, 0.f, 0.f, 0.f};
    f32x4 d = __builtin_amdgcn_mfma_f32_16x16x32_f16(bk.h, aq.h, zero, 0, 0, 0);
    uint2 pk2;
    pk2.x = pk_f16(d[0] * 0.25f, d[1] * 0.25f);
    pk2.y = pk_f16(d[2] * 0.25f, d[3] * 0.25f);
    *(uint2*)&SRS[swz(lr, s0 + 4 * lg)] = pk2;
  }
  lds_barrier();                                 // scores visible; stores/loads in flight

  // ---- Phase B: gated-on chunks only ----
  #pragma unroll
  for (int it = 0; it < 16; ++it) {
    const int ch = it >> 1;
    if (!((gbits >> ch) & 1u)) continue;
    const int s = it * 64 + lr * 4;
    const bool msk = (ch == ptch);
    f32x4 pv;
    if      (it == 0) pv = pf0;
    else if (it == 1) pv = pf1;
    else if (it == 2) pv = pf2;
    else if (it == 3) pv = pf3;
    else if (it == 4) pv = pf4;
    else if (it == 5) pv = pf5;
    else pv = __builtin_nontemporal_load((const f32x4*)(prow + s));
    union { uint2 u; f16x2 hh[2]; } sc;
    sc.u = *(const uint2*)&SRS[swz(r, s)];
    f32x4 rs;
    rs[0] = (float)sc.hh[0][0] + pv[0];
    rs[1] = (float)sc.hh[0][1] + pv[1];
    rs[2] = (float)sc.hh[1][0] + pv[2];
    rs[3] = (float)sc.hh[1][1] + pv[3];
    *(f32x4*)(rsrow + s) = rs;
    if (msk) {
      eh[it] = make_uint2(0u, 0u);
    } else {
      float e0 = __expf(rs[0]);
      float e1 = __expf(rs[1]);
      float e2 = __expf(rs[2]);
      float e3 = __expf(rs[3]);
      den += (e0 + e1) + (e2 + e3);
      eh[it].x = pk_f16(e0, e1);
      eh[it].y = pk_f16(e2, e3);
    }
    *(uint2*)&SRS[swz(r, s)] = eh[it];
  }

  #pragma unroll
  for (int off = 1; off < 16; off <<= 1)
    den += __shfl_xor(den, off);
  const float invd = 1.f / den;                  // den >= 1 always
  lds_barrier();                                 // e visible; stores NOT drained

  // ---- PV: V loads issued here (not queued behind attn stores) ----
  f32x4 acc = {0.f, 0.f, 0.f, 0.f};
  const u16* vbase = vtb + ((b * 8 + h) * 16 + lr) * 1024;
  #pragma unroll
  for (int kc = 0; kc < 8; ++kc) {
    Frag pa, bv;
    pa.i = *(const int4*)(&SRS[swz(lr, sbase + kc * 32 + 8 * lg)]);
    bv.i = *(const int4*)(vbase + sbase + kc * 32 + 8 * lg);
    acc = __builtin_amdgcn_mfma_f32_16x16x32_f16(pa.h, bv.h, acc, 0, 0, 0);
  }

  // ---- epilogue: cross-wave partial sum + DenInv via SRS-as-f32 scratch ----
  lds_barrier();                                 // all waves done reading e
  {
    float* OutBuf = (float*)SRS;                 // [64][20] f32 + DenInv[16]
    #pragma unroll
    for (int j = 0; j < 4; ++j)
      OutBuf[(w * 16 + 4 * lg + j) * 20 + lr] = acc[j];
    if (lr == 0) OutBuf[1280 + r] = invd;
  }
  lds_barrier();
  {
    float* OutBuf = (float*)SRS;
    const int pr = tid >> 4, dd = tid & 15;
    float o = (OutBuf[pr * 20 + dd] + OutBuf[(16 + pr) * 20 + dd] +
               OutBuf[(32 + pr) * 20 + dd] + OutBuf[(48 + pr) * 20 + dd]) *
              OutBuf[1280 + pr];
    preout[((b * 512 + p0 + pr) * 8 + h) * 16 + dd] = o;
  }

  // ---- attn stores LAST (masked channel already written pre-A) ----
  {
    #pragma unroll
    for (int it = 0; it < 16; ++it) {
      const int ch = it >> 1;
      if (ch == ptch) continue;                  // written pre-A
      const int s = it * 64 + lr * 4;
      union { uint2 u; f16x2 hh[2]; } e;
      e.u = eh[it];
      f32x4 o;
      o[0] = (float)e.hh[0][0] * invd;
      o[1] = (float)e.hh[0][1] * invd;
      o[2] = (float)e.hh[1][0] * invd;
      o[3] = (float)e.hh[1][1] * invd;
      *(f32x4*)(arow + s) = o;
    }
  }
}

// ---------------------------------------------------------------------------
extern "C" void kernel_launch(void* const* d_in, const int* in_sizes, int n_in,
                              void* d_out, int out_size, void* d_ws, size_t ws_size,
                              hipStream_t stream)
{
  (void)in_sizes; (void)n_in; (void)out_size; (void)ws_size;
  const float* Q       = (const float*)d_in[0];
  const float* K       = (const float*)d_in[1];
  const float* V       = (const float*)d_in[2];
  const float* prev    = (const float*)d_in[3];
  const float* Wq      = (const float*)d_in[5];
  const float* bq      = (const float*)d_in[6];
  const float* Wk      = (const float*)d_in[7];
  const float* bk      = (const float*)d_in[8];
  const float* Wv      = (const float*)d_in[9];
  const float* bv      = (const float*)d_in[10];
  const float* Wo      = (const float*)d_in[11];
  const float* bo      = (const float*)d_in[12];
  const float* ch_gate = (const float*)d_in[13];

  u16*   qb     = (u16*)d_ws;                        // 1 MB f16
  u16*   kb     = qb + 524288;                       // 2 MB f16
  u16*   vtb    = kb + 1048576;                      // 2 MB f16
  float* preout = (float*)((char*)d_ws + 5242880);   // 2 MB fp32

  float* outp     = (float*)d_out;          // (B,P,128)
  float* attn_out = outp + 524288;          // (B,P,H,S)
  float* rs_out   = outp + 34078720;        // (B,P,H,S)

  proj_qkv<<<320, 256, 0, stream>>>(Q, K, V, Wq, bq, Wk, bk, Wv, bv,
                                    qb, kb, vtb);
  attn_kernel<<<2048, 256, 0, stream>>>(qb, kb, vtb, prev, ch_gate,
                                        rs_out, attn_out, preout);
  proj_out_kernel<<<256, 256, 0, stream>>>(preout, Wo, bo, outp);
}